// Round 3
// baseline (125.084 us; speedup 1.0000x reference)
//
#include <hip/hip_runtime.h>

#define H 1024
#define W 1024
#define NIMG 8
#define TX 128
#define STRIP 64
#define NITER (STRIP / 8)             // 8
#define NBX (W / TX)                  // 8
#define NBY (H / STRIP)               // 16
#define NBLOCKS (NBX * NBY * NIMG)    // 1024
#define EPS 1e-5f

// Produce horizontal 9-box rowsums {I,J,I2,J2,IJ} for 8 px of one row into
// ring slot `slot`. XOR-swizzled px so same-row lanes spread across banks.
__device__ __forceinline__ void produce8(
    const float* __restrict__ Ib, const float* __restrict__ Jb,
    int y, int gx, int xg, int slot,
    float4 (*rs4)[TX], float (*rs1)[TX])
{
  float a[16], b[16];
  if (y >= 0 && y < H) {
    const int xbase = gx * TX + xg * 8 - 4;
    const float* Ip = Ib + (size_t)y * W;
    const float* Jp = Jb + (size_t)y * W;
    if (xbase >= 0 && xbase + 16 <= W) {
      const float4* pa = reinterpret_cast<const float4*>(Ip + xbase);
      const float4* pb = reinterpret_cast<const float4*>(Jp + xbase);
      #pragma unroll
      for (int q = 0; q < 4; ++q) {
        float4 va = pa[q], vb = pb[q];
        a[4*q+0] = va.x; a[4*q+1] = va.y; a[4*q+2] = va.z; a[4*q+3] = va.w;
        b[4*q+0] = vb.x; b[4*q+1] = vb.y; b[4*q+2] = vb.z; b[4*q+3] = vb.w;
      }
    } else {
      #pragma unroll
      for (int k = 0; k < 16; ++k) {
        int xx = xbase + k;
        bool in = (xx >= 0) && (xx < W);
        a[k] = in ? Ip[xx] : 0.0f;
        b[k] = in ? Jp[xx] : 0.0f;
      }
    }
  } else {
    #pragma unroll
    for (int k = 0; k < 16; ++k) { a[k] = 0.0f; b[k] = 0.0f; }
  }
  float sI = 0.f, sJ = 0.f, sII = 0.f, sJJ = 0.f, sIJ = 0.f;
  #pragma unroll
  for (int k = 0; k < 9; ++k) {
    sI  += a[k];        sJ  += b[k];
    sII += a[k] * a[k]; sJJ += b[k] * b[k];
    sIJ += a[k] * b[k];
  }
  const int xg8 = xg * 8;
  const int xm  = xg & 7;
  #pragma unroll
  for (int i = 0; i < 8; ++i) {
    if (i > 0) {
      float an = a[i+8], al = a[i-1], bn = b[i+8], bl = b[i-1];
      sI  += an - al;           sJ  += bn - bl;
      sII += an*an - al*al;     sJJ += bn*bn - bl*bl;
      sIJ += an*bn - al*bl;
    }
    const int px = xg8 + (i ^ xm);
    rs4[slot][px] = make_float4(sI, sJ, sII, sJJ);
    rs1[slot][px] = sIJ;
  }
}

// LDS ring: 16 rowsum rows x 128 cols x 20 B = 40960 B -> 4 blocks/CU.
__global__ __launch_bounds__(256, 4)
void ncc_main(const float* __restrict__ I, const float* __restrict__ J,
              float* __restrict__ partial) {
  __shared__ float4 rs4[16][TX];
  __shared__ float  rs1[16][TX];

  const int tid = threadIdx.x;
  const int gx = blockIdx.x, sy = blockIdx.y, n = blockIdx.z;
  const int y0 = sy * STRIP;
  const size_t img_off = (size_t)n * H * W;
  const float* Ib = I + img_off;
  const float* Jb = J + img_off;

  // ---- prologue: all 256 threads produce rowsum rows y0-4 .. y0+11 ----
  {
    const int rr = tid >> 4;                  // 0..15 -> rel row rr-4
    const int xg = tid & 15;
    produce8(Ib, Jb, y0 - 4 + rr, gx, xg, (rr + 12) & 15, rs4, rs1);
  }
  __syncthreads();

  // ---- consumer state (waves 2,3): col, register ring, running sums ----
  const int col = tid - 128;                                  // 0..127
  const int xs  = (col & ~7) | ((col ^ (col >> 3)) & 7);      // un-swizzle
  float4 h4[9]; float h1[9];                  // rows [8t-5 .. 8t+3]
  float wI = 0.f, wJ = 0.f, wII = 0.f, wJJ = 0.f, wIJ = 0.f;
  float acc = 0.f;
  if (tid >= 128) {
    h4[0] = make_float4(0.f, 0.f, 0.f, 0.f); h1[0] = 0.f;     // row -5 = pad
    #pragma unroll
    for (int j = 0; j < 8; ++j) {            // rows -4..3 -> slots 12..15,0..3
      const int s = (j + 12) & 15;
      h4[j+1] = rs4[s][xs]; h1[j+1] = rs1[s][xs];
      wI += h4[j+1].x; wJ += h4[j+1].y; wII += h4[j+1].z; wJJ += h4[j+1].w;
      wIJ += h1[j+1];
    }
  }
  __syncthreads();   // prime reads done before iter-0 producer overwrites 12..15,0..3

  const float inv81 = 1.0f / 81.0f;
  for (int t = 0; t < NITER; ++t) {
    if (tid < 128) {
      // produce rowsum rows 8t+12 .. 8t+19 (not needed after last iter)
      if (t < NITER - 1) {
        const int r  = tid >> 4;              // 0..7
        const int xg = tid & 15;
        const int rel = 8*t + 12 + r;
        produce8(Ib, Jb, y0 + rel, gx, xg, rel & 15, rs4, rs1);
      }
    } else {
      // consume: outputs rows 8t..8t+7; entering rowsum rows 8t+4..8t+11
      const int sb = (8*t + 4) & 15;          // 4 or 12
      float4 n4[8]; float n1[8];
      #pragma unroll
      for (int j = 0; j < 8; ++j) {
        const int s = (sb + j) & 15;
        n4[j] = rs4[s][xs]; n1[j] = rs1[s][xs];
      }
      #pragma unroll
      for (int i = 0; i < 8; ++i) {
        wI  += n4[i].x - h4[i].x;  wJ  += n4[i].y - h4[i].y;
        wII += n4[i].z - h4[i].z;  wJJ += n4[i].w - h4[i].w;
        wIJ += n1[i]   - h1[i];
        float cross = fmaf(-(wI * wJ), inv81, wIJ);
        float Iv    = fmaf(-(wI * wI), inv81, wII);
        float Jv    = fmaf(-(wJ * wJ), inv81, wJJ);
        acc = fmaf(cross * cross,
                   __builtin_amdgcn_rcpf(fmaf(Iv, Jv, EPS)), acc);
      }
      // rotate carry: h' = rows [8t+3 .. 8t+11] = { h[8], n[0..7] }
      h4[0] = h4[8]; h1[0] = h1[8];
      #pragma unroll
      for (int j = 1; j < 9; ++j) { h4[j] = n4[j-1]; h1[j] = n1[j-1]; }
    }
    __syncthreads();
  }

  // ---- block reduction (producers hold acc=0) ----
  #pragma unroll
  for (int off = 32; off > 0; off >>= 1)
    acc += __shfl_down(acc, off, 64);
  if ((tid & 63) == 0) rs1[0][tid >> 6] = acc;
  __syncthreads();
  if (tid == 0) {
    const int blin = blockIdx.x + NBX * (blockIdx.y + NBY * (int)blockIdx.z);
    partial[blin] = rs1[0][0] + rs1[0][1] + rs1[0][2] + rs1[0][3];
  }
}

__global__ __launch_bounds__(256)
void ncc_reduce(const float* __restrict__ partial, float* __restrict__ out) {
  __shared__ float red[4];
  const int tid = threadIdx.x;
  float s = 0.f;
  #pragma unroll 4
  for (int i = tid; i < NBLOCKS; i += 256) s += partial[i];
  #pragma unroll
  for (int off = 32; off > 0; off >>= 1)
    s += __shfl_down(s, off, 64);
  if ((tid & 63) == 0) red[tid >> 6] = s;
  __syncthreads();
  if (tid == 0)
    out[0] = (red[0] + red[1] + red[2] + red[3]) *
             (1.0f / (float)((size_t)NIMG * H * W));
}

extern "C" void kernel_launch(void* const* d_in, const int* in_sizes, int n_in,
                              void* d_out, int out_size, void* d_ws, size_t ws_size,
                              hipStream_t stream) {
  const float* I = (const float*)d_in[0];
  const float* J = (const float*)d_in[1];
  float* out     = (float*)d_out;
  float* partial = (float*)d_ws;            // 1024 * 4 B

  dim3 grid(NBX, NBY, NIMG);                // 8 x 16 x 8 = 1024 blocks, 4/CU
  hipLaunchKernelGGL(ncc_main, grid, dim3(256), 0, stream, I, J, partial);
  hipLaunchKernelGGL(ncc_reduce, dim3(1), dim3(256), 0, stream, partial, out);
}

// Round 4
// 112.650 us; speedup vs baseline: 1.1104x; 1.1104x over previous
//
#include <hip/hip_runtime.h>

#define H 1024
#define W 1024
#define NIMG 8
#define TX 64
#define CY 8
#define RS_ROWS (CY + 8)            // 16 rowsum rows per tile
#define NBX (W / TX)                // 16
#define NBY (H / CY)                // 128
#define NBLOCKS (NBX * NBY * NIMG)  // 16384
#define EPS 1e-5f

// LDS: rs4 = 16*64*16 = 16384 B, rs1 = 16*64*4 = 4096 B -> 20480 B total
// -> exactly 8 blocks/CU (160 KiB). 2-wave blocks: barriers are near-free.
__global__ __launch_bounds__(128, 4)
void ncc_main(const float* __restrict__ I, const float* __restrict__ J,
              float* __restrict__ partial) {
  __shared__ float4 rs4[RS_ROWS][TX];
  __shared__ float  rs1[RS_ROWS][TX];

  const int tid = threadIdx.x;
  const int gx = blockIdx.x, gy = blockIdx.y, n = blockIdx.z;
  const size_t img_off = (size_t)n * H * W;

  // ---------- Phase 1: horizontal 9-box sums; exactly 1 unit per thread ----
  {
    const int r  = tid >> 3;            // rowsum row 0..15
    const int xg = tid & 7;             // x-group of 8 px
    const int y  = gy * CY + r - 4;     // global row (zero-pad outside)
    float a[16], b[16];
    if (y >= 0 && y < H) {
      const int xbase = gx * TX + xg * 8 - 4;
      const float* Ip = I + img_off + (size_t)y * W;
      const float* Jp = J + img_off + (size_t)y * W;
      if (xbase >= 0 && xbase + 16 <= W) {
        const float4* pa = reinterpret_cast<const float4*>(Ip + xbase);
        const float4* pb = reinterpret_cast<const float4*>(Jp + xbase);
        #pragma unroll
        for (int q = 0; q < 4; ++q) {
          float4 va = pa[q], vb = pb[q];
          a[4*q+0] = va.x; a[4*q+1] = va.y; a[4*q+2] = va.z; a[4*q+3] = va.w;
          b[4*q+0] = vb.x; b[4*q+1] = vb.y; b[4*q+2] = vb.z; b[4*q+3] = vb.w;
        }
      } else {
        #pragma unroll
        for (int k = 0; k < 16; ++k) {
          int xx = xbase + k;
          bool in = (xx >= 0) && (xx < W);
          a[k] = in ? Ip[xx] : 0.0f;
          b[k] = in ? Jp[xx] : 0.0f;
        }
      }
    } else {
      #pragma unroll
      for (int k = 0; k < 16; ++k) { a[k] = 0.0f; b[k] = 0.0f; }
    }
    float sI = 0.f, sJ = 0.f, sII = 0.f, sJJ = 0.f, sIJ = 0.f;
    #pragma unroll
    for (int k = 0; k < 9; ++k) {
      sI  += a[k];        sJ  += b[k];
      sII += a[k] * a[k]; sJJ += b[k] * b[k];
      sIJ += a[k] * b[k];
    }
    const int xg8 = xg * 8;
    #pragma unroll
    for (int i = 0; i < 8; ++i) {
      if (i > 0) {
        float an = a[i+8], al = a[i-1], bn = b[i+8], bl = b[i-1];
        sI  += an - al;           sJ  += bn - bl;
        sII += an*an - al*al;     sJJ += bn*bn - bl*bl;
        sIJ += an*bn - al*bl;
      }
      // XOR swizzle: same-row lanes (stride 8 float4s) spread across banks
      const int px = xg8 + (i ^ xg);
      rs4[r][px] = make_float4(sI, sJ, sII, sJJ);
      rs1[r][px] = sIJ;
    }
  }
  __syncthreads();

  // ---------- Phase 2: vertical 9-box + cc; 64 cols x 2 halves x 4 rows ----
  const int x  = tid & 63;
  const int h  = tid >> 6;                          // 0/1 -> rows [4h, 4h+4)
  const int xs = (x & ~7) | ((x ^ (x >> 3)) & 7);   // un-swizzle (const)
  const int base = h * 4;
  float4 rows4[9]; float rows1[9];
  float wI = 0.f, wJ = 0.f, wII = 0.f, wJJ = 0.f, wIJ = 0.f;
  #pragma unroll
  for (int k = 0; k < 9; ++k) {
    rows4[k] = rs4[base + k][xs];
    rows1[k] = rs1[base + k][xs];
    wI += rows4[k].x; wJ += rows4[k].y; wII += rows4[k].z; wJJ += rows4[k].w;
    wIJ += rows1[k];
  }
  const float inv81 = 1.0f / 81.0f;
  float acc = 0.f;
  #pragma unroll
  for (int i = 0; i < 4; ++i) {
    if (i > 0) {
      float4 e4 = rs4[base + 8 + i][xs];
      float  e1 = rs1[base + 8 + i][xs];
      wI  += e4.x - rows4[i-1].x;  wJ  += e4.y - rows4[i-1].y;
      wII += e4.z - rows4[i-1].z;  wJJ += e4.w - rows4[i-1].w;
      wIJ += e1   - rows1[i-1];
    }
    float cross = fmaf(-(wI * wJ), inv81, wIJ);
    float Iv    = fmaf(-(wI * wI), inv81, wII);
    float Jv    = fmaf(-(wJ * wJ), inv81, wJJ);
    acc = fmaf(cross * cross,
               __builtin_amdgcn_rcpf(fmaf(Iv, Jv, EPS)), acc);
  }

  // ---------- block reduction -> partial (reuse rs1 as scratch) ----------
  #pragma unroll
  for (int off = 32; off > 0; off >>= 1)
    acc += __shfl_down(acc, off, 64);
  __syncthreads();                       // all rs reads done before reuse
  if ((tid & 63) == 0) rs1[0][tid >> 6] = acc;
  __syncthreads();
  if (tid == 0) {
    const int blin = blockIdx.x + NBX * (blockIdx.y + NBY * (int)blockIdx.z);
    partial[blin] = rs1[0][0] + rs1[0][1];
  }
}

__global__ __launch_bounds__(256)
void ncc_reduce(const float* __restrict__ partial, float* __restrict__ out) {
  __shared__ float red[4];
  const int tid = threadIdx.x;
  float s = 0.f;
  #pragma unroll 8
  for (int i = tid; i < NBLOCKS; i += 256) s += partial[i];
  #pragma unroll
  for (int off = 32; off > 0; off >>= 1)
    s += __shfl_down(s, off, 64);
  if ((tid & 63) == 0) red[tid >> 6] = s;
  __syncthreads();
  if (tid == 0)
    out[0] = (red[0] + red[1] + red[2] + red[3]) *
             (1.0f / (float)((size_t)NIMG * H * W));
}

extern "C" void kernel_launch(void* const* d_in, const int* in_sizes, int n_in,
                              void* d_out, int out_size, void* d_ws, size_t ws_size,
                              hipStream_t stream) {
  const float* I = (const float*)d_in[0];
  const float* J = (const float*)d_in[1];
  float* out     = (float*)d_out;
  float* partial = (float*)d_ws;            // 16384 * 4 B = 64 KiB scratch

  dim3 grid(NBX, NBY, NIMG);                // 16 x 128 x 8 = 16384 blocks
  hipLaunchKernelGGL(ncc_main, grid, dim3(128), 0, stream, I, J, partial);
  hipLaunchKernelGGL(ncc_reduce, dim3(1), dim3(256), 0, stream, partial, out);
}